// Round 1
// baseline (660.061 us; speedup 1.0000x reference)
//
#include <hip/hip_runtime.h>
#include <hip/hip_bf16.h>
#include <stdint.h>
#include <math.h>

#define B_ 2
#define S_ 2048
#define E_ 2048
#define H_ 16
#define D_ 128
#define M_ (B_*S_)

typedef _Float16 half8 __attribute__((ext_vector_type(8)));
typedef _Float16 half4 __attribute__((ext_vector_type(4)));
typedef float    floatx4 __attribute__((ext_vector_type(4)));

// ---------------------------------------------------------------------------
// async global->LDS, 16B per lane. LDS dest must be wave-uniform base; HW
// writes lane L at base + L*16.
__device__ __forceinline__ void async_copy16(const void* g, void* lds_base) {
    __builtin_amdgcn_global_load_lds(
        (__attribute__((address_space(1))) void*)(uintptr_t)g,
        (__attribute__((address_space(3))) void*)(uint32_t)(uintptr_t)lds_base,
        16, 0, 0);
}

// ---------------------------------------------------------------------------
// fp32 -> fp16 cast, vectorized x4
__global__ __launch_bounds__(256) void cast_f32_f16(
    const float* __restrict__ in, _Float16* __restrict__ out, int n4)
{
    int i = blockIdx.x * 256 + threadIdx.x;
    if (i < n4) {
        floatx4 v = ((const floatx4*)in)[i];
        ((half4*)out)[i] = __builtin_convertvector(v, half4);
    }
}

// ---------------------------------------------------------------------------
// C[M,N] = A[M,K] · W[N,K]^T  (both K-contiguous row-major), f16 MFMA,
// m97 structure: 128x128 tile, BK=32, global_load_lds width=16.
template<bool BIAS, typename OutT>
__global__ __launch_bounds__(256) void gemm_bt(
    const _Float16* __restrict__ A, const _Float16* __restrict__ W,
    OutT* __restrict__ C, const float* __restrict__ bias,
    int M, int N, int K)
{
    __shared__ __align__(16) _Float16 As[128*32];
    __shared__ __align__(16) _Float16 Bs[128*32];
    const int tid  = threadIdx.x;
    const int lane = tid & 63;
    const int wave = tid >> 6;
    const int wm = wave >> 1, wn = wave & 1;      // 2x2 waves, 64x64 each
    const int fr = lane & 15, fg = lane >> 4;
    const int m0 = blockIdx.x * 128;
    const int n0 = blockIdx.y * 128;

    floatx4 acc[4][4] = {};

    for (int k0 = 0; k0 < K; k0 += 32) {
        __syncthreads();
        // stage A and B tiles: 8 chunks of 512 elems each, 2 chunks per wave
#pragma unroll
        for (int i = 0; i < 2; ++i) {
            int c = wave * 2 + i;
            int e = c * 512 + lane * 8;           // element index in [128][32] tile
            int row = e >> 5, col = e & 31;
            async_copy16(A + (size_t)(m0 + row) * K + k0 + col, &As[c * 512]);
            async_copy16(W + (size_t)(n0 + row) * K + k0 + col, &Bs[c * 512]);
        }
        __syncthreads();

        half8 a[4], b[4];
#pragma unroll
        for (int t = 0; t < 4; ++t) {
            a[t] = *(const half8*)&As[(wm*64 + t*16 + fr) * 32 + fg*8];
            b[t] = *(const half8*)&Bs[(wn*64 + t*16 + fr) * 32 + fg*8];
        }
#pragma unroll
        for (int mt = 0; mt < 4; ++mt)
#pragma unroll
            for (int nt = 0; nt < 4; ++nt)
                acc[mt][nt] = __builtin_amdgcn_mfma_f32_16x16x32_f16(
                    a[mt], b[nt], acc[mt][nt], 0, 0, 0);
    }

    // epilogue: C row = (lane>>4)*4 + reg, col = lane&15 (per 16x16 tile)
#pragma unroll
    for (int mt = 0; mt < 4; ++mt)
#pragma unroll
        for (int nt = 0; nt < 4; ++nt) {
            int col = n0 + wn*64 + nt*16 + fr;
            float bv = BIAS ? bias[col] : 0.f;
#pragma unroll
            for (int r = 0; r < 4; ++r) {
                int row = m0 + wm*64 + mt*16 + fg*4 + r;
                C[(size_t)row * N + col] = (OutT)(acc[mt][nt][r] + bv);
            }
        }
}

// ---------------------------------------------------------------------------
// V [B,S,H*D] (f16) -> Vt [B*H, D, S] (f16), LDS-tiled 64x64 transpose
__global__ __launch_bounds__(256) void transpose_v(
    const _Float16* __restrict__ V, _Float16* __restrict__ Vt)
{
    __shared__ __align__(16) _Float16 t[64][72];
    const int bh = blockIdx.z;
    const int b = bh >> 4, h = bh & 15;
    const int s0 = blockIdx.x * 64, d0 = blockIdx.y * 64;
    const int tid = threadIdx.x;
#pragma unroll
    for (int i = 0; i < 2; ++i) {
        int e = (i*256 + tid) * 8;
        int row = e >> 6, col = e & 63;           // row = s, col = d
        *(half8*)&t[row][col] =
            *(const half8*)&V[(size_t)(b*S_ + s0 + row) * E_ + h*D_ + d0 + col];
    }
    __syncthreads();
#pragma unroll
    for (int i = 0; i < 2; ++i) {
        int e = (i*256 + tid) * 8;
        int dr = e >> 6, col = e & 63;            // dr = d, col = s
        half8 v;
#pragma unroll
        for (int j = 0; j < 8; ++j) v[j] = t[col + j][dr];
        *(half8*)&Vt[((size_t)bh * D_ + d0 + dr) * S_ + s0 + col] = v;
    }
}

// ---------------------------------------------------------------------------
// causal flash attention. Q,K: [B,S,H*D] f16.  Vt: [B*H,D,S] f16.
// O: [B,S,H*D] f16.  One block = (q-tile of 64) x (b,h); 4 waves, each wave
// owns a 16-row Q strip.
__global__ __launch_bounds__(256) void attn_causal(
    const _Float16* __restrict__ Q, const _Float16* __restrict__ K,
    const _Float16* __restrict__ Vt, _Float16* __restrict__ O)
{
    const int qt = blockIdx.x;
    const int bh = blockIdx.y;
    const int b = bh >> 4, h = bh & 15;
    const int tid = threadIdx.x, lane = tid & 63, wave = tid >> 6;
    const int fr = lane & 15, fg = lane >> 4;

    __shared__ __align__(16) _Float16 Ks[64*136];    // [kcol][d], stride 136
    __shared__ __align__(16) _Float16 Vs[128*72];    // [d][kcol], stride 72
    __shared__ __align__(16) _Float16 Ps[4][16*72];  // per-wave P strip

    // Q fragments for this wave's 16-row strip: A[m=fr][k=kk*32+fg*8+j]
    const _Float16* qbase = Q + (size_t)(b*S_ + qt*64 + wave*16 + fr) * E_ + h*D_;
    half8 qf[4];
#pragma unroll
    for (int kk = 0; kk < 4; ++kk)
        qf[kk] = *(const half8*)&qbase[kk*32 + fg*8];

    float m_i[4], l_i[4];
    floatx4 o[8] = {};
#pragma unroll
    for (int r = 0; r < 4; ++r) { m_i[r] = -INFINITY; l_i[r] = 0.f; }

    const float scale = 0.088388347648318447f;   // 1/sqrt(128)

    for (int jt = 0; jt <= qt; ++jt) {
        __syncthreads();
        // stage K-tile [64][128] and Vt-tile [128][64] (padded strides)
#pragma unroll
        for (int i = 0; i < 4; ++i) {
            int e = (i*256 + tid) * 8;
            { int row = e >> 7, col = e & 127;
              *(half8*)&Ks[row*136 + col] =
                  *(const half8*)&K[(size_t)(b*S_ + jt*64 + row) * E_ + h*D_ + col]; }
            { int row = e >> 6, col = e & 63;
              *(half8*)&Vs[row*72 + col] =
                  *(const half8*)&Vt[((size_t)bh * D_ + row) * S_ + jt*64 + col]; }
        }
        __syncthreads();

        // S = Q K^T for this wave's strip: 4 n-tiles x 4 k-steps
        floatx4 sacc[4] = {};
#pragma unroll
        for (int kk = 0; kk < 4; ++kk)
#pragma unroll
            for (int nt = 0; nt < 4; ++nt) {
                half8 bf = *(const half8*)&Ks[(nt*16 + fr)*136 + kk*32 + fg*8];
                sacc[nt] = __builtin_amdgcn_mfma_f32_16x16x32_f16(
                    qf[kk], bf, sacc[nt], 0, 0, 0);
            }

        // online softmax (rows = fg*4 + r, cols distributed over 16 lanes)
        const int qr0 = qt*64 + wave*16 + fg*4;
        const int kc0 = jt*64 + fr;
        float alpha[4];
#pragma unroll
        for (int r = 0; r < 4; ++r) {
            float mx = -INFINITY;
#pragma unroll
            for (int nt = 0; nt < 4; ++nt) {
                float s = sacc[nt][r] * scale;
                s = (kc0 + nt*16 <= qr0 + r) ? s : -INFINITY;
                sacc[nt][r] = s;
                mx = fmaxf(mx, s);
            }
            mx = fmaxf(mx, __shfl_xor(mx, 1));
            mx = fmaxf(mx, __shfl_xor(mx, 2));
            mx = fmaxf(mx, __shfl_xor(mx, 4));
            mx = fmaxf(mx, __shfl_xor(mx, 8));
            float mnew = fmaxf(m_i[r], mx);
            alpha[r] = (m_i[r] == -INFINITY) ? 0.f : __expf(m_i[r] - mnew);
            float rs = 0.f;
#pragma unroll
            for (int nt = 0; nt < 4; ++nt) {
                float p = __expf(sacc[nt][r] - mnew);   // exp(-inf)=0 handles mask
                sacc[nt][r] = p;
                rs += p;
            }
            rs += __shfl_xor(rs, 1);
            rs += __shfl_xor(rs, 2);
            rs += __shfl_xor(rs, 4);
            rs += __shfl_xor(rs, 8);
            l_i[r] = alpha[r] * l_i[r] + rs;
            m_i[r] = mnew;
        }
#pragma unroll
        for (int dt = 0; dt < 8; ++dt)
#pragma unroll
            for (int r = 0; r < 4; ++r) o[dt][r] *= alpha[r];

        // P: C-layout -> A-layout via wave-local LDS strip
#pragma unroll
        for (int nt = 0; nt < 4; ++nt)
#pragma unroll
            for (int r = 0; r < 4; ++r)
                Ps[wave][(fg*4 + r)*72 + nt*16 + fr] = (_Float16)sacc[nt][r];
        __syncthreads();   // cross-lane LDS RAW (conservative; also uniform)

        // O += P · V  (B-operand = Vt rows, k = seq contiguous)
#pragma unroll
        for (int kk = 0; kk < 2; ++kk) {
            half8 pf = *(const half8*)&Ps[wave][fr*72 + kk*32 + fg*8];
#pragma unroll
            for (int dt = 0; dt < 8; ++dt) {
                half8 vf = *(const half8*)&Vs[(dt*16 + fr)*72 + kk*32 + fg*8];
                o[dt] = __builtin_amdgcn_mfma_f32_16x16x32_f16(pf, vf, o[dt], 0, 0, 0);
            }
        }
    }

    // epilogue: O[s][h*D+d] = o / l
    _Float16* ob = O + (size_t)(b*S_ + qt*64 + wave*16) * E_ + h*D_;
#pragma unroll
    for (int r = 0; r < 4; ++r) {
        float inv = 1.f / l_i[r];
#pragma unroll
        for (int dt = 0; dt < 8; ++dt)
            ob[(size_t)(fg*4 + r) * E_ + dt*16 + fr] = (_Float16)(o[dt][r] * inv);
    }
}

// ---------------------------------------------------------------------------
extern "C" void kernel_launch(void* const* d_in, const int* in_sizes, int n_in,
                              void* d_out, int out_size, void* d_ws, size_t ws_size,
                              hipStream_t stream) {
    const float* X  = (const float*)d_in[0];
    const float* Wq = (const float*)d_in[1];
    const float* Wk = (const float*)d_in[2];
    const float* Wv = (const float*)d_in[3];
    const float* Wo = (const float*)d_in[4];
    const float* bo = (const float*)d_in[5];
    float* out = (float*)d_out;

    const size_t ME = (size_t)M_ * E_;   // 8,388,608
    const size_t EE = (size_t)E_ * E_;   // 4,194,304
    _Float16* ws  = (_Float16*)d_ws;
    _Float16* Xh  = ws;
    _Float16* Wqh = Xh  + ME;
    _Float16* Wkh = Wqh + EE;
    _Float16* Wvh = Wkh + EE;
    _Float16* Woh = Wvh + EE;
    _Float16* Qh  = Woh + EE;
    _Float16* Kh  = Qh  + ME;
    _Float16* Vh  = Kh  + ME;
    _Float16* Vth = Xh;   // Xh dead after the QKV GEMMs
    _Float16* Oh  = Vh;   // V dead after the transpose
    // total ws use: 96 MiB

    cast_f32_f16<<<dim3(ME/4/256), dim3(256), 0, stream>>>(X,  Xh,  (int)(ME/4));
    cast_f32_f16<<<dim3(EE/4/256), dim3(256), 0, stream>>>(Wq, Wqh, (int)(EE/4));
    cast_f32_f16<<<dim3(EE/4/256), dim3(256), 0, stream>>>(Wk, Wkh, (int)(EE/4));
    cast_f32_f16<<<dim3(EE/4/256), dim3(256), 0, stream>>>(Wv, Wvh, (int)(EE/4));
    cast_f32_f16<<<dim3(EE/4/256), dim3(256), 0, stream>>>(Wo, Woh, (int)(EE/4));

    dim3 gg(M_/128, E_/128);
    gemm_bt<false, _Float16><<<gg, dim3(256), 0, stream>>>(Xh, Wqh, Qh, nullptr, M_, E_, E_);
    gemm_bt<false, _Float16><<<gg, dim3(256), 0, stream>>>(Xh, Wkh, Kh, nullptr, M_, E_, E_);
    gemm_bt<false, _Float16><<<gg, dim3(256), 0, stream>>>(Xh, Wvh, Vh, nullptr, M_, E_, E_);

    transpose_v<<<dim3(S_/64, D_/64, B_*H_), dim3(256), 0, stream>>>(Vh, Vth);

    attn_causal<<<dim3(S_/64, B_*H_), dim3(256), 0, stream>>>(Qh, Kh, Vth, Oh);

    gemm_bt<true, float><<<gg, dim3(256), 0, stream>>>(Oh, Woh, out, bo, M_, E_, E_);
}

// Round 2
// 496.552 us; speedup vs baseline: 1.3293x; 1.3293x over previous
//
#include <hip/hip_runtime.h>
#include <hip/hip_bf16.h>
#include <stdint.h>
#include <math.h>

#define B_ 2
#define S_ 2048
#define E_ 2048
#define H_ 16
#define D_ 128
#define M_ (B_*S_)

typedef _Float16 half8 __attribute__((ext_vector_type(8)));
typedef _Float16 half4 __attribute__((ext_vector_type(4)));
typedef float    floatx4 __attribute__((ext_vector_type(4)));

// ---------------------------------------------------------------------------
// async global->LDS, 16B per lane. LDS dest must be wave-uniform base; HW
// writes lane L at base + L*16.
__device__ __forceinline__ void async_copy16(const void* g, void* lds_base) {
    __builtin_amdgcn_global_load_lds(
        (__attribute__((address_space(1))) void*)(uintptr_t)g,
        (__attribute__((address_space(3))) void*)(uint32_t)(uintptr_t)lds_base,
        16, 0, 0);
}

// ---------------------------------------------------------------------------
// fused fp32 -> fp16 cast for X + 4 weights, one launch (z selects tensor)
__global__ __launch_bounds__(256) void cast_all(
    const float* __restrict__ X,  const float* __restrict__ Wq,
    const float* __restrict__ Wk, const float* __restrict__ Wv,
    const float* __restrict__ Wo,
    _Float16* __restrict__ Xh,  _Float16* __restrict__ Wqh,
    _Float16* __restrict__ Wkh, _Float16* __restrict__ Wvh,
    _Float16* __restrict__ Woh)
{
    const int z = blockIdx.z;
    const float* in; _Float16* out; int n4;
    const int ME4 = M_*E_/4, EE4 = E_*E_/4;
    switch (z) {
        case 0: in = X;  out = Xh;  n4 = ME4; break;
        case 1: in = Wq; out = Wqh; n4 = EE4; break;
        case 2: in = Wk; out = Wkh; n4 = EE4; break;
        case 3: in = Wv; out = Wvh; n4 = EE4; break;
        default: in = Wo; out = Woh; n4 = EE4; break;
    }
    int i = blockIdx.x * 256 + threadIdx.x;
    if (i < n4) {
        floatx4 v = ((const floatx4*)in)[i];
        ((half4*)out)[i] = __builtin_convertvector(v, half4);
    }
}

// ---------------------------------------------------------------------------
// C[M,N] = A[M,K] · W[N,K]^T  (both K-contiguous row-major), f16 MFMA,
// m97 structure: 128x128 tile, BK=32, global_load_lds width=16.
// QKV variant: grid.z selects one of three weight/output pairs.
template<bool BIAS, typename OutT, int NW>
__global__ __launch_bounds__(256) void gemm_bt(
    const _Float16* __restrict__ A,
    const _Float16* __restrict__ W0, const _Float16* __restrict__ W1,
    const _Float16* __restrict__ W2,
    OutT* __restrict__ C0, OutT* __restrict__ C1, OutT* __restrict__ C2,
    const float* __restrict__ bias, int M, int N, int K)
{
    const _Float16* W = W0; OutT* C = C0;
    if (NW > 1) {
        if (blockIdx.z == 1) { W = W1; C = C1; }
        else if (blockIdx.z == 2) { W = W2; C = C2; }
    }
    __shared__ __align__(16) _Float16 As[128*32];
    __shared__ __align__(16) _Float16 Bs[128*32];
    const int tid  = threadIdx.x;
    const int lane = tid & 63;
    const int wave = tid >> 6;
    const int wm = wave >> 1, wn = wave & 1;      // 2x2 waves, 64x64 each
    const int fr = lane & 15, fg = lane >> 4;
    const int m0 = blockIdx.x * 128;
    const int n0 = blockIdx.y * 128;

    floatx4 acc[4][4] = {};

    for (int k0 = 0; k0 < K; k0 += 32) {
        __syncthreads();
#pragma unroll
        for (int i = 0; i < 2; ++i) {
            int c = wave * 2 + i;
            int e = c * 512 + lane * 8;           // element index in [128][32] tile
            int row = e >> 5, col = e & 31;
            async_copy16(A + (size_t)(m0 + row) * K + k0 + col, &As[c * 512]);
            async_copy16(W + (size_t)(n0 + row) * K + k0 + col, &Bs[c * 512]);
        }
        __syncthreads();

        half8 a[4], b[4];
#pragma unroll
        for (int t = 0; t < 4; ++t) {
            a[t] = *(const half8*)&As[(wm*64 + t*16 + fr) * 32 + fg*8];
            b[t] = *(const half8*)&Bs[(wn*64 + t*16 + fr) * 32 + fg*8];
        }
#pragma unroll
        for (int mt = 0; mt < 4; ++mt)
#pragma unroll
            for (int nt = 0; nt < 4; ++nt)
                acc[mt][nt] = __builtin_amdgcn_mfma_f32_16x16x32_f16(
                    a[mt], b[nt], acc[mt][nt], 0, 0, 0);
    }

#pragma unroll
    for (int mt = 0; mt < 4; ++mt)
#pragma unroll
        for (int nt = 0; nt < 4; ++nt) {
            int col = n0 + wn*64 + nt*16 + fr;
            float bv = BIAS ? bias[col] : 0.f;
#pragma unroll
            for (int r = 0; r < 4; ++r) {
                int row = m0 + wm*64 + mt*16 + fg*4 + r;
                C[(size_t)row * N + col] = (OutT)(acc[mt][nt][r] + bv);
            }
        }
}

// ---------------------------------------------------------------------------
// V [B,S,H*D] (f16) -> Vt [B*H, D, S] (f16), LDS-tiled 64x64 transpose
__global__ __launch_bounds__(256) void transpose_v(
    const _Float16* __restrict__ V, _Float16* __restrict__ Vt)
{
    __shared__ __align__(16) _Float16 t[64][72];
    const int bh = blockIdx.z;
    const int b = bh >> 4, h = bh & 15;
    const int s0 = blockIdx.x * 64, d0 = blockIdx.y * 64;
    const int tid = threadIdx.x;
#pragma unroll
    for (int i = 0; i < 2; ++i) {
        int e = (i*256 + tid) * 8;
        int row = e >> 6, col = e & 63;           // row = s, col = d
        *(half8*)&t[row][col] =
            *(const half8*)&V[(size_t)(b*S_ + s0 + row) * E_ + h*D_ + d0 + col];
    }
    __syncthreads();
#pragma unroll
    for (int i = 0; i < 2; ++i) {
        int e = (i*256 + tid) * 8;
        int dr = e >> 6, col = e & 63;            // dr = d, col = s
        half8 v;
#pragma unroll
        for (int j = 0; j < 8; ++j) v[j] = t[col + j][dr];
        *(half8*)&Vt[((size_t)bh * D_ + d0 + dr) * S_ + s0 + col] = v;
    }
}

// ---------------------------------------------------------------------------
// Wave-autonomous causal flash attention — ZERO block barriers.
// Each wave owns a 32-row Q strip of one (b,h); K and Vt fragments are read
// directly from global in MFMA B-layout (16 rows x 64B runs, L2/L3-served).
// P's C->A layout transform goes through a wave-private LDS strip (intra-wave
// lgkmcnt ordering only). Load balance: block i's waves take strips
// {2i, 2i+1, 62-2i, 63-2i} -> every block does exactly 66 jt-iterations.
__global__ __launch_bounds__(256, 2) void attn_causal_wave(
    const _Float16* __restrict__ Q, const _Float16* __restrict__ K,
    const _Float16* __restrict__ Vt, _Float16* __restrict__ O)
{
    const int ib = blockIdx.x;                 // 0..15
    const int bh = blockIdx.y;
    const int b = bh >> 4, h = bh & 15;
    const int tid = threadIdx.x, lane = tid & 63, wave = tid >> 6;
    const int fr = lane & 15, fg = lane >> 4;

    __shared__ __align__(16) _Float16 Ps[4][32*72];   // per-wave P strip

    const int qs = (wave < 2) ? (2*ib + wave) : (62 - 2*ib + (wave - 2));
    const int iters = (qs >> 1) + 1;           // k-tiles of 64 needed

    // Q fragments: A[m=fr][k=fg*8+j], 2 sub-tiles of 16 rows, 4 k-steps
    const _Float16* qb = Q + ((size_t)(b*S_) + qs*32) * E_ + h*D_;
    half8 qf[2][4];
#pragma unroll
    for (int mt = 0; mt < 2; ++mt)
#pragma unroll
        for (int kk = 0; kk < 4; ++kk)
            qf[mt][kk] = *(const half8*)&qb[(size_t)(mt*16 + fr) * E_ + kk*32 + fg*8];

    float m_i[2][4], l_i[2][4];
    floatx4 o[2][8] = {};
#pragma unroll
    for (int mt = 0; mt < 2; ++mt)
#pragma unroll
        for (int r = 0; r < 4; ++r) { m_i[mt][r] = -INFINITY; l_i[mt][r] = 0.f; }

    const float scale = 0.088388347648318447f;   // 1/sqrt(128)
    const _Float16* kb = K + (size_t)(b*S_) * E_ + h*D_;
    const _Float16* vb = Vt + (size_t)bh * D_ * S_;
    _Float16* ps = &Ps[wave][0];

    for (int jt = 0; jt < iters; ++jt) {
        // ---- S = Q K^T (32 rows x 64 cols) -------------------------------
        floatx4 sacc[2][4] = {};
#pragma unroll
        for (int kk = 0; kk < 4; ++kk) {
            half8 bf[4];
#pragma unroll
            for (int nt = 0; nt < 4; ++nt)
                bf[nt] = *(const half8*)&kb[(size_t)(jt*64 + nt*16 + fr) * E_ + kk*32 + fg*8];
#pragma unroll
            for (int mt = 0; mt < 2; ++mt)
#pragma unroll
                for (int nt = 0; nt < 4; ++nt)
                    sacc[mt][nt] = __builtin_amdgcn_mfma_f32_16x16x32_f16(
                        qf[mt][kk], bf[nt], sacc[mt][nt], 0, 0, 0);
        }

        // ---- online softmax ----------------------------------------------
        const int kc0 = jt*64 + fr;
#pragma unroll
        for (int mt = 0; mt < 2; ++mt) {
            const int qr0 = qs*32 + mt*16 + fg*4;
            float alpha[4];
#pragma unroll
            for (int r = 0; r < 4; ++r) {
                float mx = -INFINITY;
#pragma unroll
                for (int nt = 0; nt < 4; ++nt) {
                    float s = sacc[mt][nt][r] * scale;
                    s = (kc0 + nt*16 <= qr0 + r) ? s : -INFINITY;
                    sacc[mt][nt][r] = s;
                    mx = fmaxf(mx, s);
                }
                mx = fmaxf(mx, __shfl_xor(mx, 1));
                mx = fmaxf(mx, __shfl_xor(mx, 2));
                mx = fmaxf(mx, __shfl_xor(mx, 4));
                mx = fmaxf(mx, __shfl_xor(mx, 8));
                float mnew = fmaxf(m_i[mt][r], mx);
                alpha[r] = (m_i[mt][r] == -INFINITY) ? 0.f : __expf(m_i[mt][r] - mnew);
                float rs = 0.f;
#pragma unroll
                for (int nt = 0; nt < 4; ++nt) {
                    float p = __expf(sacc[mt][nt][r] - mnew);  // exp(-inf)=0 masks
                    sacc[mt][nt][r] = p;
                    rs += p;
                }
                rs += __shfl_xor(rs, 1);
                rs += __shfl_xor(rs, 2);
                rs += __shfl_xor(rs, 4);
                rs += __shfl_xor(rs, 8);
                l_i[mt][r] = alpha[r] * l_i[mt][r] + rs;
                m_i[mt][r] = mnew;
            }
#pragma unroll
            for (int dt = 0; dt < 8; ++dt)
#pragma unroll
                for (int r = 0; r < 4; ++r) o[mt][dt][r] *= alpha[r];

            // P: C-layout -> A-layout, wave-private LDS
#pragma unroll
            for (int nt = 0; nt < 4; ++nt)
#pragma unroll
                for (int r = 0; r < 4; ++r)
                    ps[(mt*16 + fg*4 + r)*72 + nt*16 + fr] = (_Float16)sacc[mt][nt][r];
        }
        __asm__ __volatile__("s_waitcnt lgkmcnt(0)" ::: "memory");

        // ---- O += P · V (Vt rows are B-layout, k = seq contiguous) -------
#pragma unroll
        for (int kk = 0; kk < 2; ++kk) {
            half8 pf[2];
#pragma unroll
            for (int mt = 0; mt < 2; ++mt)
                pf[mt] = *(const half8*)&ps[(mt*16 + fr)*72 + kk*32 + fg*8];
#pragma unroll
            for (int dt = 0; dt < 8; ++dt) {
                half8 vf = *(const half8*)&vb[(size_t)(dt*16 + fr) * S_ + jt*64 + kk*32 + fg*8];
#pragma unroll
                for (int mt = 0; mt < 2; ++mt)
                    o[mt][dt] = __builtin_amdgcn_mfma_f32_16x16x32_f16(
                        pf[mt], vf, o[mt][dt], 0, 0, 0);
            }
        }
    }

    // ---- epilogue ---------------------------------------------------------
#pragma unroll
    for (int mt = 0; mt < 2; ++mt) {
        _Float16* ob = O + ((size_t)(b*S_) + qs*32 + mt*16) * E_ + h*D_;
#pragma unroll
        for (int r = 0; r < 4; ++r) {
            float inv = 1.f / l_i[mt][r];
#pragma unroll
            for (int dt = 0; dt < 8; ++dt)
                ob[(size_t)(fg*4 + r) * E_ + dt*16 + fr] = (_Float16)(o[mt][dt][r] * inv);
        }
    }
}

// ---------------------------------------------------------------------------
extern "C" void kernel_launch(void* const* d_in, const int* in_sizes, int n_in,
                              void* d_out, int out_size, void* d_ws, size_t ws_size,
                              hipStream_t stream) {
    const float* X  = (const float*)d_in[0];
    const float* Wq = (const float*)d_in[1];
    const float* Wk = (const float*)d_in[2];
    const float* Wv = (const float*)d_in[3];
    const float* Wo = (const float*)d_in[4];
    const float* bo = (const float*)d_in[5];
    float* out = (float*)d_out;

    const size_t ME = (size_t)M_ * E_;   // 8,388,608
    const size_t EE = (size_t)E_ * E_;   // 4,194,304
    _Float16* ws  = (_Float16*)d_ws;
    _Float16* Xh  = ws;
    _Float16* Wqh = Xh  + ME;
    _Float16* Wkh = Wqh + EE;
    _Float16* Wvh = Wkh + EE;
    _Float16* Woh = Wvh + EE;
    _Float16* Qh  = Woh + EE;
    _Float16* Kh  = Qh  + ME;
    _Float16* Vh  = Kh  + ME;
    _Float16* Vth = Xh;   // Xh dead after the QKV GEMMs
    _Float16* Oh  = Vh;   // V dead after the transpose

    cast_all<<<dim3(ME/4/256, 1, 5), dim3(256), 0, stream>>>(
        X, Wq, Wk, Wv, Wo, Xh, Wqh, Wkh, Wvh, Woh);

    gemm_bt<false, _Float16, 3><<<dim3(M_/128, E_/128, 3), dim3(256), 0, stream>>>(
        Xh, Wqh, Wkh, Wvh, Qh, Kh, Vh, nullptr, M_, E_, E_);

    transpose_v<<<dim3(S_/64, D_/64, B_*H_), dim3(256), 0, stream>>>(Vh, Vth);

    attn_causal_wave<<<dim3(16, B_*H_), dim3(256), 0, stream>>>(Qh, Kh, Vth, Oh);

    gemm_bt<true, float, 1><<<dim3(M_/128, E_/128, 1), dim3(256), 0, stream>>>(
        Oh, Woh, nullptr, nullptr, out, nullptr, nullptr, bo, M_, E_, E_);
}